// Round 19
// baseline (306.401 us; speedup 1.0000x reference)
//
#include <hip/hip_runtime.h>

#define F 128
#define RB 64
#define RB_SHIFT 6
#define CAP 4096
#define SCH 4096
#define PT3 1024
#define EPT3 (SCH / PT3)   // 4 edges per thread in scatter
#define NSEG 8
#define COL_BITS 17
#define COL_MASK 0x1FFFF
#define MAXNB 2048
#define NQ 4
#define QSHIFT 15          // col >> 15 -> quartile (col < 131072)
#define NKEY (NQ * RB)     // 256 sort keys

// ---- fused: per-chunk histogram (low blockIdx) + weight fp32->biased-u8 (rest) ----
__global__ __launch_bounds__(256) void cvt_chist_kernel(
    const float4* __restrict__ w4, uint* __restrict__ wq32, float* __restrict__ scales,
    int total4, const int* __restrict__ rows, int* __restrict__ cntmat, int n_edges,
    int nb, int nchunks) {
    if ((int)blockIdx.x < nchunks) {
        __shared__ int h[MAXNB];
        int c = blockIdx.x, t = threadIdx.x;
        for (int i = t; i < nb; i += 256) h[i] = 0;
        __syncthreads();
        int e0 = c * SCH, e1 = min(e0 + SCH, n_edges);
        if (e1 - e0 == SCH) {
            const int4* r4 = (const int4*)(rows + e0);
#pragma unroll
            for (int k = 0; k < 4; k++) {
                int4 rv = r4[k * 256 + t];
                atomicAdd(&h[rv.x >> RB_SHIFT], 1);
                atomicAdd(&h[rv.y >> RB_SHIFT], 1);
                atomicAdd(&h[rv.z >> RB_SHIFT], 1);
                atomicAdd(&h[rv.w >> RB_SHIFT], 1);
            }
        } else {
            for (int e = e0 + t; e < e1; e += 256) atomicAdd(&h[rows[e] >> RB_SHIFT], 1);
        }
        __syncthreads();
        for (int i = t; i < nb; i += 256) cntmat[(size_t)c * nb + i] = h[i];
    } else {
        int idx = (blockIdx.x - nchunks) * 256 + threadIdx.x;
        if (idx >= total4) return;
        float4 f = w4[idx];
        float m = fmaxf(fmaxf(fabsf(f.x), fabsf(f.y)), fmaxf(fabsf(f.z), fabsf(f.w)));
#pragma unroll
        for (int off = 1; off <= 16; off <<= 1) m = fmaxf(m, __shfl_xor(m, off));
        float inv = m > 0.f ? 127.f / m : 0.f;
        int q0 = (int)rintf(f.x * inv) + 128;  // biased, 1..255
        int q1 = (int)rintf(f.y * inv) + 128;
        int q2 = (int)rintf(f.z * inv) + 128;
        int q3 = (int)rintf(f.w * inv) + 128;
        wq32[idx] = (uint)(q0 | (q1 << 8) | (q2 << 16) | (q3 << 24));
        if ((idx & 31) == 0) scales[idx >> 5] = m * (1.f / 127.f);
    }
}

// ---- P2a: per-segment exclusive scan along chunks (lane-per-bucket) ----
__global__ __launch_bounds__(256) void scanA_kernel(int* __restrict__ cntmat,
                                                    int* __restrict__ segsum,
                                                    int nb, int nchunks) {
    int b = blockIdx.x * 256 + threadIdx.x;
    if (b >= nb) return;
    int sg = blockIdx.y;
    int cps = (nchunks + NSEG - 1) / NSEG;
    int c0 = sg * cps, c1 = min(c0 + cps, nchunks);
    int run = 0;
#pragma unroll 4
    for (int c = c0; c < c1; c++) {
        int v = cntmat[(size_t)c * nb + b];
        cntmat[(size_t)c * nb + b] = run;
        run += v;
    }
    segsum[sg * nb + b] = run;
}

// ---- P2b merged: scan segment sums per bucket, then block-scan -> boffs ----
__global__ void scanBC_kernel(int* __restrict__ segsum, int* __restrict__ boffs, int nb) {
    __shared__ int lds[1024];
    int t = threadIdx.x;
    int per = (nb + 1023) / 1024;  // <= 2 since nb <= MAXNB
    int base = t * per;
    int cnt[2] = {0, 0};
    int s = 0;
    for (int i = 0; i < per && i < 2; i++) {
        int b = base + i;
        int run = 0;
        if (b < nb) {
            for (int sg = 0; sg < NSEG; sg++) {
                int v = segsum[sg * nb + b];
                segsum[sg * nb + b] = run;
                run += v;
            }
        }
        cnt[i] = run;
        s += run;
    }
    lds[t] = s;
    __syncthreads();
    for (int off = 1; off < 1024; off <<= 1) {
        int a = (t >= off) ? lds[t - off] : 0;
        __syncthreads();
        lds[t] += a;
        __syncthreads();
    }
    int excl = lds[t] - s;
    for (int i = 0; i < per && i < 2; i++) {
        int b = base + i;
        if (b < nb) {
            boffs[b] = excl;
            excl += cnt[i];
        }
    }
    if (t == 1023) boffs[nb] = lds[1023];
}

// ---- P3: exact-position scatter (wave-level scan), LDS-sorted contiguous writes ----
__global__ __launch_bounds__(PT3) void scatter_kernel(
    const int* __restrict__ rows, const int* __restrict__ cols,
    const float* __restrict__ vals, const float* __restrict__ scales,
    const int* __restrict__ boffs, const int* __restrict__ segsum,
    const int* __restrict__ cntmat, int2* __restrict__ epk, int n_edges, int nb,
    int nchunks) {
    __shared__ int relc[MAXNB];
    __shared__ int hist[MAXNB];
    __shared__ int lcur[MAXNB];
    __shared__ int2 buf[SCH];
    __shared__ ushort sbkt[SCH];
    __shared__ int wsum[PT3 / 64], wbase[PT3 / 64];
    int t = threadIdx.x;
    int lane = t & 63, w = t >> 6;
    int cps = (nchunks + NSEG - 1) / NSEG;
    int c = blockIdx.x;

    int e0 = c * SCH, e1 = min(e0 + SCH, n_edges);
    int cnt = e1 - e0;
    int sg = c / cps;

    for (int i = t; i < nb; i += PT3) {
        relc[i] = boffs[i] + segsum[sg * nb + i] + cntmat[(size_t)c * nb + i];
        hist[i] = 0;
    }
    __syncthreads();

    int er[EPT3], ec[EPT3];
    float ev[EPT3];
    int eb = e0 + (t << 2);
    if (eb + 4 <= e1) {
        int4 rv = *(const int4*)(rows + eb);
        int4 cv = *(const int4*)(cols + eb);
        float4 vv = *(const float4*)(vals + eb);
        er[0] = rv.x; er[1] = rv.y; er[2] = rv.z; er[3] = rv.w;
        ec[0] = cv.x; ec[1] = cv.y; ec[2] = cv.z; ec[3] = cv.w;
        ev[0] = vv.x * scales[ec[0]];
        ev[1] = vv.y * scales[ec[1]];
        ev[2] = vv.z * scales[ec[2]];
        ev[3] = vv.w * scales[ec[3]];
#pragma unroll
        for (int k = 0; k < 4; k++) atomicAdd(&hist[er[k] >> RB_SHIFT], 1);
    } else {
#pragma unroll
        for (int k = 0; k < 4; k++) {
            int e = eb + k;
            if (e < e1) {
                er[k] = rows[e];
                ec[k] = cols[e];
                ev[k] = vals[e] * scales[ec[k]];
                atomicAdd(&hist[er[k] >> RB_SHIFT], 1);
            }
        }
    }
    __syncthreads();

    int b0 = t << 1;  // MAXNB / PT3 == 2
    int h0 = (b0 + 0 < nb) ? hist[b0 + 0] : 0;
    int h1 = (b0 + 1 < nb) ? hist[b0 + 1] : 0;
    int psum = h0 + h1;
    int v = psum;
#pragma unroll
    for (int off = 1; off < 64; off <<= 1) {
        int a = __shfl_up(v, off);
        if (lane >= off) v += a;
    }
    if (lane == 63) wsum[w] = v;
    __syncthreads();
    if (t == 0) {
        int run = 0;
        for (int i = 0; i < PT3 / 64; i++) {
            wbase[i] = run;
            run += wsum[i];
        }
    }
    __syncthreads();
    int excl = v - psum + wbase[w];
    if (b0 + 0 < nb) { lcur[b0 + 0] = excl; relc[b0 + 0] -= excl; }
    excl += h0;
    if (b0 + 1 < nb) { lcur[b0 + 1] = excl; relc[b0 + 1] -= excl; }
    __syncthreads();

#pragma unroll
    for (int k = 0; k < EPT3; k++) {
        int e = eb + k;
        if (e < e1) {
            int b = er[k] >> RB_SHIFT;
            int p = atomicAdd(&lcur[b], 1);
            buf[p] = make_int2(ec[k] | ((er[k] & (RB - 1)) << COL_BITS),
                               __float_as_int(ev[k]));
            sbkt[p] = (ushort)b;
        }
    }
    __syncthreads();

    for (int i = t; i < cnt; i += PT3) epk[relc[sbkt[i]] + i] = buf[i];
}

// ---- fused: LDS (quartile,row)-sort + biased-u8 gather (half-wave/edge) ----
__global__ __launch_bounds__(512, 8) void sortacc_kernel(
    const int* __restrict__ boffs, const int2* __restrict__ epk,
    const uint* __restrict__ wq32, const float* __restrict__ bias,
    float* __restrict__ out, int n_nodes) {
    __shared__ int2 buf[CAP];  // 32 KB
    __shared__ int hist[NKEY], lstart[NKEY], lcur[NKEY];
    int b = blockIdx.x;
    int s = boffs[b];
    int cnt = boffs[b + 1] - s;
    int row0 = b << RB_SHIFT;
    int t = threadIdx.x;
    int lane = t & 63, w = t >> 6;
    int half = lane >> 5;   // 0/1: which edge of a pair
    int c32 = lane & 31;    // feature group: features 4*c32 .. 4*c32+3
    float4 bb4 = ((const float4*)bias)[c32];

#define B0(u) ((float)((u) & 0xFFu))
#define B1(u) ((float)(((u) >> 8) & 0xFFu))
#define B2(u) ((float)(((u) >> 16) & 0xFFu))
#define B3(u) ((float)((u) >> 24))
// key = (col_quartile << 6) | row_local, from packed rk.x
#define KEY(px) (((((uint)(px) >> QSHIFT) & (NQ - 1)) << RB_SHIFT) | ((uint)(px) >> COL_BITS))

    if (cnt <= CAP) {
        if (t < NKEY) hist[t] = 0;
        __syncthreads();
        int2 r0, r1, r2, r3, r4, r5, r6, r7;
#define LOADK(rk, k)                                                     \
        {                                                                \
            int i = t + (k)*512;                                         \
            if (i < cnt) {                                               \
                rk = epk[s + i];                                         \
                atomicAdd(&hist[KEY(rk.x)], 1);                          \
            }                                                            \
        }
        LOADK(r0, 0) LOADK(r1, 1) LOADK(r2, 2) LOADK(r3, 3)
        LOADK(r4, 4) LOADK(r5, 5) LOADK(r6, 6) LOADK(r7, 7)
#undef LOADK
        __syncthreads();
        if (w == 0) {  // wave-level exclusive scan of 256 keys, 4 per lane
            int k0 = lane << 2;
            int h0 = hist[k0], h1 = hist[k0 + 1], h2 = hist[k0 + 2], h3 = hist[k0 + 3];
            int psum = h0 + h1 + h2 + h3;
            int v = psum;
#pragma unroll
            for (int off = 1; off < 64; off <<= 1) {
                int a = __shfl_up(v, off);
                if (lane >= off) v += a;
            }
            int excl = v - psum;
            lstart[k0] = excl; lcur[k0] = excl; excl += h0;
            lstart[k0 + 1] = excl; lcur[k0 + 1] = excl; excl += h1;
            lstart[k0 + 2] = excl; lcur[k0 + 2] = excl; excl += h2;
            lstart[k0 + 3] = excl; lcur[k0 + 3] = excl;
        }
        __syncthreads();
        // scatter: store col pre-shifted for wq32 addressing (col*32)
#define SCATK(rk, k)                                                         \
        {                                                                    \
            int i = t + (k)*512;                                             \
            if (i < cnt) {                                                   \
                int p = atomicAdd(&lcur[KEY(rk.x)], 1);                      \
                buf[p] = make_int2((int)(((uint)rk.x & COL_MASK) << 5), rk.y);\
            }                                                                \
        }
        SCATK(r0, 0) SCATK(r1, 1) SCATK(r2, 2) SCATK(r3, 3)
        SCATK(r4, 4) SCATK(r5, 5) SCATK(r6, 6) SCATK(r7, 7)
#undef SCATK
        __syncthreads();

        // quartile-major accumulate: wave w owns rows w*8..w*8+7
        float ax0[8], ax1[8], ax2[8], ax3[8], svs[8];
#pragma unroll
        for (int j = 0; j < 8; j++) {
            ax0[j] = 0.f; ax1[j] = 0.f; ax2[j] = 0.f; ax3[j] = 0.f; svs[j] = 0.f;
        }
        for (int q = 0; q < NQ; q++) {
#pragma unroll
            for (int j = 0; j < 8; j++) {
                int key = (q << RB_SHIFT) | (w * 8 + j);
                int e = lstart[key];
                int end = e + hist[key];
                float a0 = 0.f, a1 = 0.f, a2 = 0.f, a3 = 0.f, sv = 0.f;
                for (; e + 6 <= end; e += 6) {  // 3 pairs in flight per half
                    int2 p0 = buf[e + 0 + half];
                    int2 p1 = buf[e + 2 + half];
                    int2 p2 = buf[e + 4 + half];
                    uint u0 = wq32[(uint)p0.x + c32];
                    uint u1 = wq32[(uint)p1.x + c32];
                    uint u2 = wq32[(uint)p2.x + c32];
                    float v0 = __int_as_float(p0.y);
                    float v1 = __int_as_float(p1.y);
                    float v2 = __int_as_float(p2.y);
                    a0 += v0 * B0(u0) + v1 * B0(u1) + v2 * B0(u2);
                    a1 += v0 * B1(u0) + v1 * B1(u1) + v2 * B1(u2);
                    a2 += v0 * B2(u0) + v1 * B2(u1) + v2 * B2(u2);
                    a3 += v0 * B3(u0) + v1 * B3(u1) + v2 * B3(u2);
                    sv += (v0 + v1) + v2;
                }
                for (; e + 2 <= end; e += 2) {
                    int2 pk = buf[e + half];
                    uint u = wq32[(uint)pk.x + c32];
                    float v = __int_as_float(pk.y);
                    a0 += v * B0(u); a1 += v * B1(u);
                    a2 += v * B2(u); a3 += v * B3(u);
                    sv += v;
                }
                if (e < end && half == 0) {  // odd tail
                    int2 pk = buf[e];
                    uint u = wq32[(uint)pk.x + c32];
                    float v = __int_as_float(pk.y);
                    a0 += v * B0(u); a1 += v * B1(u);
                    a2 += v * B2(u); a3 += v * B3(u);
                    sv += v;
                }
                ax0[j] += a0; ax1[j] += a1; ax2[j] += a2; ax3[j] += a3; svs[j] += sv;
            }
        }
#pragma unroll
        for (int j = 0; j < 8; j++) {
            int gr = row0 + w * 8 + j;
            float a0 = ax0[j] + __shfl_xor(ax0[j], 32);
            float a1 = ax1[j] + __shfl_xor(ax1[j], 32);
            float a2 = ax2[j] + __shfl_xor(ax2[j], 32);
            float a3 = ax3[j] + __shfl_xor(ax3[j], 32);
            float sv = svs[j] + __shfl_xor(svs[j], 32);
            if (gr < n_nodes && half == 0) {
                float corr = 128.f * sv;
                ((float4*)out)[(size_t)gr * 32 + c32] =
                    make_float4(a0 - corr + bb4.x, a1 - corr + bb4.y,
                                a2 - corr + bb4.z, a3 - corr + bb4.w);
            }
        }
    } else {
        // overflow bucket: filter scan from global (correct, ~never taken)
        for (int j = 0; j < 8; j++) {
            int rl = w * 8 + j;
            int gr = row0 + rl;
            if (gr >= n_nodes) break;
            float a0 = 0.f, a1 = 0.f, a2 = 0.f, a3 = 0.f, sv = 0.f;
            if (half == 0) {
                for (int e = s; e < s + cnt; ++e) {
                    int2 pk = epk[e];
                    if ((int)((unsigned)pk.x >> COL_BITS) == rl) {
                        uint u = wq32[(((uint)pk.x & COL_MASK) << 5) + c32];
                        float v = __int_as_float(pk.y);
                        a0 += v * B0(u); a1 += v * B1(u);
                        a2 += v * B2(u); a3 += v * B3(u);
                        sv += v;
                    }
                }
            }
            a0 += __shfl_xor(a0, 32);
            a1 += __shfl_xor(a1, 32);
            a2 += __shfl_xor(a2, 32);
            a3 += __shfl_xor(a3, 32);
            sv += __shfl_xor(sv, 32);
            if (half == 0) {
                float corr = 128.f * sv;
                ((float4*)out)[(size_t)gr * 32 + c32] =
                    make_float4(a0 - corr + bb4.x, a1 - corr + bb4.y,
                                a2 - corr + bb4.z, a3 - corr + bb4.w);
            }
        }
    }
#undef B0
#undef B1
#undef B2
#undef B3
#undef KEY
}

// ---------------- fallback: atomic path (fp32, exact) ----------------
__global__ void init_out_kernel(float* __restrict__ out, const float* __restrict__ bias,
                                int n_nodes) {
    const float4* b4 = (const float4*)bias;
    float4* o4 = (float4*)out;
    int total = n_nodes * (F / 4);
    for (int i = blockIdx.x * blockDim.x + threadIdx.x; i < total;
         i += gridDim.x * blockDim.x)
        o4[i] = b4[i & (F / 4 - 1)];
}

__global__ void edge_scatter_kernel(const int* __restrict__ rows,
                                    const int* __restrict__ cols,
                                    const float* __restrict__ vals,
                                    const float* __restrict__ weight,
                                    float* __restrict__ out, int n_edges) {
    int e = (blockIdx.x * blockDim.x + threadIdx.x) >> 6;
    if (e >= n_edges) return;
    int lane = threadIdx.x & 63;
    float2 w = ((const float2*)(weight + (size_t)cols[e] * F))[lane];
    float val = vals[e];
    float* o = out + (size_t)rows[e] * F + lane * 2;
    unsafeAtomicAdd(o, val * w.x);
    unsafeAtomicAdd(o + 1, val * w.y);
}

extern "C" void kernel_launch(void* const* d_in, const int* in_sizes, int n_in,
                              void* d_out, int out_size, void* d_ws, size_t ws_size,
                              hipStream_t stream) {
    const int*   rows   = (const int*)d_in[0];
    const int*   cols   = (const int*)d_in[1];
    const float* vals   = (const float*)d_in[2];
    const float* weight = (const float*)d_in[3];
    const float* bias   = (const float*)d_in[4];
    float* out = (float*)d_out;

    int n_edges = in_sizes[0];
    int n_nodes = out_size / F;
    int nb = (n_nodes + RB - 1) / RB;
    int nchunks = (n_edges + SCH - 1) / SCH;

    // ws: boffs[nb+1] | pad8 | epk[E] | scales[N] | pad | wq32[N*32]
    //     | pad | cntmat[nchunks*nb] | segsum[NSEG*nb]
    size_t head_ints  = ((size_t)nb + 2) & ~(size_t)1;
    size_t epk_off    = head_ints * 4;
    size_t scales_off = epk_off + (size_t)n_edges * 8;
    size_t wq_off     = (scales_off + (size_t)n_nodes * 4 + 255) & ~(size_t)255;
    size_t mat_off    = (wq_off + (size_t)n_nodes * F + 255) & ~(size_t)255;
    size_t seg_off    = mat_off + (size_t)nchunks * nb * 4;
    size_t need       = seg_off + (size_t)NSEG * nb * 4;

    if (ws_size < need || n_nodes > (1 << COL_BITS) || nb > MAXNB) {
        init_out_kernel<<<2048, 256, 0, stream>>>(out, bias, n_nodes);
        int grid = (n_edges + 3) / 4;
        edge_scatter_kernel<<<grid, 256, 0, stream>>>(rows, cols, vals, weight, out,
                                                      n_edges);
        return;
    }

    int* boffs    = (int*)d_ws;  // nb+1
    int2* epk     = (int2*)((char*)d_ws + epk_off);
    float* scales = (float*)((char*)d_ws + scales_off);
    uint* wq32    = (uint*)((char*)d_ws + wq_off);
    int* cntmat   = (int*)((char*)d_ws + mat_off);
    int* segsum   = (int*)((char*)d_ws + seg_off);

    int total4 = n_nodes * (F / 4);
    int cvt_blocks = (total4 + 255) / 256;
    cvt_chist_kernel<<<nchunks + cvt_blocks, 256, 0, stream>>>(
        (const float4*)weight, wq32, scales, total4, rows, cntmat, n_edges, nb, nchunks);
    dim3 ga((nb + 255) / 256, NSEG);
    scanA_kernel<<<ga, 256, 0, stream>>>(cntmat, segsum, nb, nchunks);
    scanBC_kernel<<<1, 1024, 0, stream>>>(segsum, boffs, nb);
    scatter_kernel<<<nchunks, PT3, 0, stream>>>(rows, cols, vals, scales, boffs, segsum,
                                                cntmat, epk, n_edges, nb, nchunks);
    sortacc_kernel<<<nb, 512, 0, stream>>>(boffs, epk, wq32, bias, out, n_nodes);
}

// Round 20
// 145.276 us; speedup vs baseline: 2.1091x; 2.1091x over previous
//
#include <hip/hip_runtime.h>

#define F 128
#define RB 64
#define RB_SHIFT 6
#define CAP 4096
#define SCH 4096
#define PT3 1024
#define EPT3 (SCH / PT3)   // 4 edges per thread in scatter
#define NSEG 8
#define COL_BITS 17
#define COL_MASK 0x1FFFF
#define MAXNB 2048

// ---- fused: per-chunk histogram (low blockIdx) + weight fp32->biased-u8 (rest) ----
__global__ __launch_bounds__(256) void cvt_chist_kernel(
    const float4* __restrict__ w4, uint* __restrict__ wq32, float* __restrict__ scales,
    int total4, const int* __restrict__ rows, int* __restrict__ cntmat, int n_edges,
    int nb, int nchunks) {
    if ((int)blockIdx.x < nchunks) {
        __shared__ int h[MAXNB];
        int c = blockIdx.x, t = threadIdx.x;
        for (int i = t; i < nb; i += 256) h[i] = 0;
        __syncthreads();
        int e0 = c * SCH, e1 = min(e0 + SCH, n_edges);
        if (e1 - e0 == SCH) {
            const int4* r4 = (const int4*)(rows + e0);
#pragma unroll
            for (int k = 0; k < 4; k++) {
                int4 rv = r4[k * 256 + t];
                atomicAdd(&h[rv.x >> RB_SHIFT], 1);
                atomicAdd(&h[rv.y >> RB_SHIFT], 1);
                atomicAdd(&h[rv.z >> RB_SHIFT], 1);
                atomicAdd(&h[rv.w >> RB_SHIFT], 1);
            }
        } else {
            for (int e = e0 + t; e < e1; e += 256) atomicAdd(&h[rows[e] >> RB_SHIFT], 1);
        }
        __syncthreads();
        for (int i = t; i < nb; i += 256) cntmat[(size_t)c * nb + i] = h[i];
    } else {
        int idx = (blockIdx.x - nchunks) * 256 + threadIdx.x;
        if (idx >= total4) return;
        float4 f = w4[idx];
        float m = fmaxf(fmaxf(fabsf(f.x), fabsf(f.y)), fmaxf(fabsf(f.z), fabsf(f.w)));
#pragma unroll
        for (int off = 1; off <= 16; off <<= 1) m = fmaxf(m, __shfl_xor(m, off));
        float inv = m > 0.f ? 127.f / m : 0.f;
        int q0 = (int)rintf(f.x * inv) + 128;  // biased, 1..255
        int q1 = (int)rintf(f.y * inv) + 128;
        int q2 = (int)rintf(f.z * inv) + 128;
        int q3 = (int)rintf(f.w * inv) + 128;
        wq32[idx] = (uint)(q0 | (q1 << 8) | (q2 << 16) | (q3 << 24));
        if ((idx & 31) == 0) scales[idx >> 5] = m * (1.f / 127.f);
    }
}

// ---- P2a: per-segment exclusive scan along chunks (lane-per-bucket) ----
__global__ __launch_bounds__(256) void scanA_kernel(int* __restrict__ cntmat,
                                                    int* __restrict__ segsum,
                                                    int nb, int nchunks) {
    int b = blockIdx.x * 256 + threadIdx.x;
    if (b >= nb) return;
    int sg = blockIdx.y;
    int cps = (nchunks + NSEG - 1) / NSEG;
    int c0 = sg * cps, c1 = min(c0 + cps, nchunks);
    int run = 0;
#pragma unroll 4
    for (int c = c0; c < c1; c++) {
        int v = cntmat[(size_t)c * nb + b];
        cntmat[(size_t)c * nb + b] = run;
        run += v;
    }
    segsum[sg * nb + b] = run;
}

// ---- P2b merged: scan segment sums per bucket, then block-scan -> boffs ----
__global__ void scanBC_kernel(int* __restrict__ segsum, int* __restrict__ boffs, int nb) {
    __shared__ int lds[1024];
    int t = threadIdx.x;
    int per = (nb + 1023) / 1024;  // <= 2 since nb <= MAXNB
    int base = t * per;
    int cnt[2] = {0, 0};
    int s = 0;
    for (int i = 0; i < per && i < 2; i++) {
        int b = base + i;
        int run = 0;
        if (b < nb) {
            for (int sg = 0; sg < NSEG; sg++) {
                int v = segsum[sg * nb + b];
                segsum[sg * nb + b] = run;
                run += v;
            }
        }
        cnt[i] = run;
        s += run;
    }
    lds[t] = s;
    __syncthreads();
    for (int off = 1; off < 1024; off <<= 1) {
        int a = (t >= off) ? lds[t - off] : 0;
        __syncthreads();
        lds[t] += a;
        __syncthreads();
    }
    int excl = lds[t] - s;
    for (int i = 0; i < per && i < 2; i++) {
        int b = base + i;
        if (b < nb) {
            boffs[b] = excl;
            excl += cnt[i];
        }
    }
    if (t == 1023) boffs[nb] = lds[1023];
}

// ---- P3: exact-position scatter (wave-level scan), LDS-sorted contiguous writes ----
__global__ __launch_bounds__(PT3) void scatter_kernel(
    const int* __restrict__ rows, const int* __restrict__ cols,
    const float* __restrict__ vals, const float* __restrict__ scales,
    const int* __restrict__ boffs, const int* __restrict__ segsum,
    const int* __restrict__ cntmat, int2* __restrict__ epk, int n_edges, int nb,
    int nchunks) {
    __shared__ int relc[MAXNB];
    __shared__ int hist[MAXNB];
    __shared__ int lcur[MAXNB];
    __shared__ int2 buf[SCH];
    __shared__ ushort sbkt[SCH];
    __shared__ int wsum[PT3 / 64], wbase[PT3 / 64];
    int t = threadIdx.x;
    int lane = t & 63, w = t >> 6;
    int cps = (nchunks + NSEG - 1) / NSEG;
    int c = blockIdx.x;

    int e0 = c * SCH, e1 = min(e0 + SCH, n_edges);
    int cnt = e1 - e0;
    int sg = c / cps;

    for (int i = t; i < nb; i += PT3) {
        relc[i] = boffs[i] + segsum[sg * nb + i] + cntmat[(size_t)c * nb + i];
        hist[i] = 0;
    }
    __syncthreads();

    int er[EPT3], ec[EPT3];
    float ev[EPT3];
    int eb = e0 + (t << 2);
    if (eb + 4 <= e1) {
        int4 rv = *(const int4*)(rows + eb);
        int4 cv = *(const int4*)(cols + eb);
        float4 vv = *(const float4*)(vals + eb);
        er[0] = rv.x; er[1] = rv.y; er[2] = rv.z; er[3] = rv.w;
        ec[0] = cv.x; ec[1] = cv.y; ec[2] = cv.z; ec[3] = cv.w;
        ev[0] = vv.x * scales[ec[0]];
        ev[1] = vv.y * scales[ec[1]];
        ev[2] = vv.z * scales[ec[2]];
        ev[3] = vv.w * scales[ec[3]];
#pragma unroll
        for (int k = 0; k < 4; k++) atomicAdd(&hist[er[k] >> RB_SHIFT], 1);
    } else {
#pragma unroll
        for (int k = 0; k < 4; k++) {
            int e = eb + k;
            if (e < e1) {
                er[k] = rows[e];
                ec[k] = cols[e];
                ev[k] = vals[e] * scales[ec[k]];
                atomicAdd(&hist[er[k] >> RB_SHIFT], 1);
            }
        }
    }
    __syncthreads();

    int b0 = t << 1;  // MAXNB / PT3 == 2
    int h0 = (b0 + 0 < nb) ? hist[b0 + 0] : 0;
    int h1 = (b0 + 1 < nb) ? hist[b0 + 1] : 0;
    int psum = h0 + h1;
    int v = psum;
#pragma unroll
    for (int off = 1; off < 64; off <<= 1) {
        int a = __shfl_up(v, off);
        if (lane >= off) v += a;
    }
    if (lane == 63) wsum[w] = v;
    __syncthreads();
    if (t == 0) {
        int run = 0;
        for (int i = 0; i < PT3 / 64; i++) {
            wbase[i] = run;
            run += wsum[i];
        }
    }
    __syncthreads();
    int excl = v - psum + wbase[w];
    if (b0 + 0 < nb) { lcur[b0 + 0] = excl; relc[b0 + 0] -= excl; }
    excl += h0;
    if (b0 + 1 < nb) { lcur[b0 + 1] = excl; relc[b0 + 1] -= excl; }
    __syncthreads();

#pragma unroll
    for (int k = 0; k < EPT3; k++) {
        int e = eb + k;
        if (e < e1) {
            int b = er[k] >> RB_SHIFT;
            int p = atomicAdd(&lcur[b], 1);
            buf[p] = make_int2(ec[k] | ((er[k] & (RB - 1)) << COL_BITS),
                               __float_as_int(ev[k]));
            sbkt[p] = (ushort)b;
        }
    }
    __syncthreads();

    for (int i = t; i < cnt; i += PT3) epk[relc[sbkt[i]] + i] = buf[i];
}

// ---- fused: LDS row-sort + biased-u8 gather (half-wave per edge) + bias + write ----
__global__ __launch_bounds__(512, 8) void sortacc_kernel(
    const int* __restrict__ boffs, const int2* __restrict__ epk,
    const uint* __restrict__ wq32, const float* __restrict__ bias,
    float* __restrict__ out, int n_nodes) {
    __shared__ int2 buf[CAP];  // 32 KB
    __shared__ int hist[RB], lstart[RB], lcur[RB];
    int b = blockIdx.x;
    int s = boffs[b];
    int cnt = boffs[b + 1] - s;
    int row0 = b << RB_SHIFT;
    int t = threadIdx.x;
    int lane = t & 63, w = t >> 6;
    int half = lane >> 5;   // 0: even edge of pair, 1: odd edge
    int c32 = lane & 31;    // feature group: features 4*c32 .. 4*c32+3
    float4 bb4 = ((const float4*)bias)[c32];

#define B0(u) ((float)((u) & 0xFFu))
#define B1(u) ((float)(((u) >> 8) & 0xFFu))
#define B2(u) ((float)(((u) >> 16) & 0xFFu))
#define B3(u) ((float)((u) >> 24))

    if (cnt <= CAP) {
        if (t < RB) hist[t] = 0;
        __syncthreads();
        int2 r0, r1, r2, r3, r4, r5, r6, r7;
#define LOADK(rk, k)                                                     \
        {                                                                \
            int i = t + (k)*512;                                         \
            if (i < cnt) {                                               \
                rk = epk[s + i];                                         \
                atomicAdd(&hist[(unsigned)rk.x >> COL_BITS], 1);         \
            }                                                            \
        }
        LOADK(r0, 0) LOADK(r1, 1) LOADK(r2, 2) LOADK(r3, 3)
        LOADK(r4, 4) LOADK(r5, 5) LOADK(r6, 6) LOADK(r7, 7)
#undef LOADK
        __syncthreads();
        if (w == 0) {
            int hv = hist[lane];
            int v = hv;
#pragma unroll
            for (int off = 1; off < 64; off <<= 1) {
                int a = __shfl_up(v, off);
                if (lane >= off) v += a;
            }
            lstart[lane] = v - hv;
            lcur[lane] = v - hv;
        }
        __syncthreads();
        // scatter: store col pre-shifted for wq32 addressing (col*32)
#define SCATK(rk, k)                                                         \
        {                                                                    \
            int i = t + (k)*512;                                             \
            if (i < cnt) {                                                   \
                int p = atomicAdd(&lcur[(unsigned)rk.x >> COL_BITS], 1);     \
                buf[p] = make_int2((int)(((uint)rk.x & COL_MASK) << 5), rk.y);\
            }                                                                \
        }
        SCATK(r0, 0) SCATK(r1, 1) SCATK(r2, 2) SCATK(r3, 3)
        SCATK(r4, 4) SCATK(r5, 5) SCATK(r6, 6) SCATK(r7, 7)
#undef SCATK
        __syncthreads();

        // wave w accumulates rows w*8 .. w*8+7; half-wave per edge, 6 pairs deep
        for (int j = 0; j < 8; j++) {
            int rl = w * 8 + j;
            int gr = row0 + rl;
            if (gr >= n_nodes) break;
            int e = lstart[rl];
            int end = e + hist[rl];
            float ax0 = 0.f, ax1 = 0.f, ax2 = 0.f, ax3 = 0.f, sv = 0.f;
            for (; e + 12 <= end; e += 12) {
                int2 p0 = buf[e + 0 + half], p1 = buf[e + 2 + half];
                int2 p2 = buf[e + 4 + half], p3 = buf[e + 6 + half];
                int2 p4 = buf[e + 8 + half], p5 = buf[e + 10 + half];
                uint u0 = wq32[(uint)p0.x + c32];
                uint u1 = wq32[(uint)p1.x + c32];
                uint u2 = wq32[(uint)p2.x + c32];
                uint u3 = wq32[(uint)p3.x + c32];
                uint u4 = wq32[(uint)p4.x + c32];
                uint u5 = wq32[(uint)p5.x + c32];
                float v0 = __int_as_float(p0.y), v1 = __int_as_float(p1.y);
                float v2 = __int_as_float(p2.y), v3 = __int_as_float(p3.y);
                float v4 = __int_as_float(p4.y), v5 = __int_as_float(p5.y);
                ax0 += v0 * B0(u0) + v1 * B0(u1) + v2 * B0(u2) + v3 * B0(u3) +
                       v4 * B0(u4) + v5 * B0(u5);
                ax1 += v0 * B1(u0) + v1 * B1(u1) + v2 * B1(u2) + v3 * B1(u3) +
                       v4 * B1(u4) + v5 * B1(u5);
                ax2 += v0 * B2(u0) + v1 * B2(u1) + v2 * B2(u2) + v3 * B2(u3) +
                       v4 * B2(u4) + v5 * B2(u5);
                ax3 += v0 * B3(u0) + v1 * B3(u1) + v2 * B3(u2) + v3 * B3(u3) +
                       v4 * B3(u4) + v5 * B3(u5);
                sv += ((v0 + v1) + (v2 + v3)) + (v4 + v5);
            }
            for (; e + 2 <= end; e += 2) {
                int2 pk = buf[e + half];
                uint u = wq32[(uint)pk.x + c32];
                float v = __int_as_float(pk.y);
                ax0 += v * B0(u);
                ax1 += v * B1(u);
                ax2 += v * B2(u);
                ax3 += v * B3(u);
                sv += v;
            }
            if (e < end && half == 0) {  // final odd edge
                int2 pk = buf[e];
                uint u = wq32[(uint)pk.x + c32];
                float v = __int_as_float(pk.y);
                ax0 += v * B0(u);
                ax1 += v * B1(u);
                ax2 += v * B2(u);
                ax3 += v * B3(u);
                sv += v;
            }
            ax0 += __shfl_xor(ax0, 32);
            ax1 += __shfl_xor(ax1, 32);
            ax2 += __shfl_xor(ax2, 32);
            ax3 += __shfl_xor(ax3, 32);
            sv += __shfl_xor(sv, 32);
            if (half == 0) {
                float corr = 128.f * sv;
                ((float4*)out)[(size_t)gr * 32 + c32] =
                    make_float4(ax0 - corr + bb4.x, ax1 - corr + bb4.y,
                                ax2 - corr + bb4.z, ax3 - corr + bb4.w);
            }
        }
    } else {
        // overflow bucket: filter scan from global (correct, ~never taken)
        for (int j = 0; j < 8; j++) {
            int rl = w * 8 + j;
            int gr = row0 + rl;
            if (gr >= n_nodes) break;
            float ax0 = 0.f, ax1 = 0.f, ax2 = 0.f, ax3 = 0.f, sv = 0.f;
            if (half == 0) {
                for (int e = s; e < s + cnt; ++e) {
                    int2 pk = epk[e];
                    if ((int)((unsigned)pk.x >> COL_BITS) == rl) {
                        uint u = wq32[(((uint)pk.x & COL_MASK) << 5) + c32];
                        float v = __int_as_float(pk.y);
                        ax0 += v * B0(u);
                        ax1 += v * B1(u);
                        ax2 += v * B2(u);
                        ax3 += v * B3(u);
                        sv += v;
                    }
                }
            }
            ax0 += __shfl_xor(ax0, 32);
            ax1 += __shfl_xor(ax1, 32);
            ax2 += __shfl_xor(ax2, 32);
            ax3 += __shfl_xor(ax3, 32);
            sv += __shfl_xor(sv, 32);
            if (half == 0) {
                float corr = 128.f * sv;
                ((float4*)out)[(size_t)gr * 32 + c32] =
                    make_float4(ax0 - corr + bb4.x, ax1 - corr + bb4.y,
                                ax2 - corr + bb4.z, ax3 - corr + bb4.w);
            }
        }
    }
#undef B0
#undef B1
#undef B2
#undef B3
}

// ---------------- fallback: atomic path (fp32, exact) ----------------
__global__ void init_out_kernel(float* __restrict__ out, const float* __restrict__ bias,
                                int n_nodes) {
    const float4* b4 = (const float4*)bias;
    float4* o4 = (float4*)out;
    int total = n_nodes * (F / 4);
    for (int i = blockIdx.x * blockDim.x + threadIdx.x; i < total;
         i += gridDim.x * blockDim.x)
        o4[i] = b4[i & (F / 4 - 1)];
}

__global__ void edge_scatter_kernel(const int* __restrict__ rows,
                                    const int* __restrict__ cols,
                                    const float* __restrict__ vals,
                                    const float* __restrict__ weight,
                                    float* __restrict__ out, int n_edges) {
    int e = (blockIdx.x * blockDim.x + threadIdx.x) >> 6;
    if (e >= n_edges) return;
    int lane = threadIdx.x & 63;
    float2 w = ((const float2*)(weight + (size_t)cols[e] * F))[lane];
    float val = vals[e];
    float* o = out + (size_t)rows[e] * F + lane * 2;
    unsafeAtomicAdd(o, val * w.x);
    unsafeAtomicAdd(o + 1, val * w.y);
}

extern "C" void kernel_launch(void* const* d_in, const int* in_sizes, int n_in,
                              void* d_out, int out_size, void* d_ws, size_t ws_size,
                              hipStream_t stream) {
    const int*   rows   = (const int*)d_in[0];
    const int*   cols   = (const int*)d_in[1];
    const float* vals   = (const float*)d_in[2];
    const float* weight = (const float*)d_in[3];
    const float* bias   = (const float*)d_in[4];
    float* out = (float*)d_out;

    int n_edges = in_sizes[0];
    int n_nodes = out_size / F;
    int nb = (n_nodes + RB - 1) / RB;
    int nchunks = (n_edges + SCH - 1) / SCH;

    // ws: boffs[nb+1] | pad8 | epk[E] | scales[N] | pad | wq32[N*32]
    //     | pad | cntmat[nchunks*nb] | segsum[NSEG*nb]
    size_t head_ints  = ((size_t)nb + 2) & ~(size_t)1;
    size_t epk_off    = head_ints * 4;
    size_t scales_off = epk_off + (size_t)n_edges * 8;
    size_t wq_off     = (scales_off + (size_t)n_nodes * 4 + 255) & ~(size_t)255;
    size_t mat_off    = (wq_off + (size_t)n_nodes * F + 255) & ~(size_t)255;
    size_t seg_off    = mat_off + (size_t)nchunks * nb * 4;
    size_t need       = seg_off + (size_t)NSEG * nb * 4;

    if (ws_size < need || n_nodes > (1 << COL_BITS) || nb > MAXNB) {
        init_out_kernel<<<2048, 256, 0, stream>>>(out, bias, n_nodes);
        int grid = (n_edges + 3) / 4;
        edge_scatter_kernel<<<grid, 256, 0, stream>>>(rows, cols, vals, weight, out,
                                                      n_edges);
        return;
    }

    int* boffs    = (int*)d_ws;  // nb+1
    int2* epk     = (int2*)((char*)d_ws + epk_off);
    float* scales = (float*)((char*)d_ws + scales_off);
    uint* wq32    = (uint*)((char*)d_ws + wq_off);
    int* cntmat   = (int*)((char*)d_ws + mat_off);
    int* segsum   = (int*)((char*)d_ws + seg_off);

    int total4 = n_nodes * (F / 4);
    int cvt_blocks = (total4 + 255) / 256;
    cvt_chist_kernel<<<nchunks + cvt_blocks, 256, 0, stream>>>(
        (const float4*)weight, wq32, scales, total4, rows, cntmat, n_edges, nb, nchunks);
    dim3 ga((nb + 255) / 256, NSEG);
    scanA_kernel<<<ga, 256, 0, stream>>>(cntmat, segsum, nb, nchunks);
    scanBC_kernel<<<1, 1024, 0, stream>>>(segsum, boffs, nb);
    scatter_kernel<<<nchunks, PT3, 0, stream>>>(rows, cols, vals, scales, boffs, segsum,
                                                cntmat, epk, n_edges, nb, nchunks);
    sortacc_kernel<<<nb, 512, 0, stream>>>(boffs, epk, wq32, bias, out, n_nodes);
}